// Round 1
// baseline (13999.513 us; speedup 1.0000x reference)
//
#include <hip/hip_runtime.h>
#include <hip/hip_bf16.h>

// RQ-VAE residual quantization, MI355X gfx950.
// data [65536][256] f32, codebooks [4][1024][256] f32.
// out = [zq_stack 4*65536*256][semantic_ids 65536*4 (as float)][loss 1], all f32.
//
// Per level: bf16-MFMA approximate scores (2 passes: min, then collect
// candidates within MARGIN) + fp64 exact rescore of candidates + fused
// gather/update epilogue. Residual r is stored in the zq_stack[3] slot of
// d_out (safe: read-before-write per thread at level 3).

#define NROWS   65536
#define DIM     256
#define KCODES  1024
#define LEVELS  4
#define CH      (NROWS * DIM)          // 16777216
#define ZQ_TOTAL (LEVELS * CH)         // 67108864
#define IDS_OFF  ZQ_TOTAL
#define LOSS_OFF (ZQ_TOTAL + NROWS * LEVELS)

#define BM      128                    // rows per block
#define BKC     64                     // codes per staged chunk
#define NCHUNK  (KCODES / BKC)         // 16
#define CAP     16                     // candidate list cap per row
#define MARGIN  30.0f

typedef __attribute__((ext_vector_type(8))) short bf16x8;
typedef __attribute__((ext_vector_type(4))) float f32x4;

__device__ __forceinline__ short f2bf(float x) {
    __hip_bfloat16 h = __float2bfloat16(x);
    short r; __builtin_memcpy(&r, &h, 2); return r;
}
__device__ __forceinline__ float bf2f(unsigned short u) {
    __hip_bfloat16 h; __builtin_memcpy(&h, &u, 2); return __bfloat162float(h);
}
// swizzled byte offset inside a [rows][256] bf16 LDS tile (512 B rows)
__device__ __forceinline__ int swz(int row, int byteInRow) {
    return row * 512 + (byteInRow ^ ((row & 7) << 4));
}

// ---------------- K_prep: bf16 codebook copy + sum(c_bf16^2) ----------------
__global__ __launch_bounds__(64) void k_prep(const float* __restrict__ cb,
                                             unsigned short* __restrict__ cbw,
                                             float* __restrict__ cn2w) {
    int cr = blockIdx.x;               // 0..4095 = level*1024 + code
    int l  = threadIdx.x;              // 0..63
    const float* src = cb + (size_t)cr * DIM + l * 4;
    float4 v = *(const float4*)src;
    short b0 = f2bf(v.x), b1 = f2bf(v.y), b2 = f2bf(v.z), b3 = f2bf(v.w);
    ushort4 st; st.x = (unsigned short)b0; st.y = (unsigned short)b1;
    st.z = (unsigned short)b2; st.w = (unsigned short)b3;
    *(ushort4*)(cbw + (size_t)cr * DIM + l * 4) = st;
    float f0 = bf2f(st.x), f1 = bf2f(st.y), f2 = bf2f(st.z), f3 = bf2f(st.w);
    float sq = f0 * f0 + f1 * f1 + f2 * f2 + f3 * f3;
    #pragma unroll
    for (int m = 32; m; m >>= 1) sq += __shfl_xor(sq, m);
    if (l == 0) cn2w[cr] = sq;
}

// ---------------- K_score: per-level scores + argmin + update ----------------
__global__ __launch_bounds__(256) void k_score(
    const float* rsrc,                       // residual (or data) [N][256]
    const float* __restrict__ cbf,           // f32 codebook, this level [1024][256]
    const unsigned short* __restrict__ cbw,  // bf16 codebook, this level
    const float* __restrict__ cn2w,          // [1024] sum of bf16-c^2
    const float* zqprev,                     // zq[l-1] or null
    float* zqout,                            // zq[l]
    float* rnext,                            // next residual or null (level 3)
    float* __restrict__ ids_out,
    float* __restrict__ loss_out,
    int level)
{
    __shared__ unsigned short cbuf[BKC * DIM];   // 32 KB, swizzled
    __shared__ float cn2buf[BKC];
    __shared__ float rowmin_s[BM];
    __shared__ unsigned short cand[BM * CAP];    // 4 KB
    __shared__ int cnt[BM];
    __shared__ int winid[BM];
    __shared__ float wl[4];

    const int tid = threadIdx.x;
    const int w = tid >> 6, l = tid & 63;
    const int g = l >> 4, li = l & 15;
    const int rows0 = blockIdx.x * BM;

    // ---- A-fragments: r rows -> bf16, held in registers for both passes ----
    bf16x8 af[2][8];
    #pragma unroll
    for (int mi = 0; mi < 2; ++mi) {
        int row = rows0 + (2 * w + mi) * 16 + li;
        const float* rp = rsrc + (size_t)row * DIM;
        #pragma unroll
        for (int kk = 0; kk < 8; ++kk) {
            int d0 = kk * 32 + 8 * g;
            float4 v0 = *(const float4*)(rp + d0);
            float4 v1 = *(const float4*)(rp + d0 + 4);
            bf16x8 t;
            t[0] = f2bf(v0.x); t[1] = f2bf(v0.y); t[2] = f2bf(v0.z); t[3] = f2bf(v0.w);
            t[4] = f2bf(v1.x); t[5] = f2bf(v1.y); t[6] = f2bf(v1.z); t[7] = f2bf(v1.w);
            af[mi][kk] = t;
        }
    }

    float minv[2][4];
    float rowm[2][4];
    #pragma unroll
    for (int mi = 0; mi < 2; ++mi)
        #pragma unroll
        for (int rg = 0; rg < 4; ++rg) { minv[mi][rg] = 3.0e38f; rowm[mi][rg] = 0.f; }

    uint4 pre[8]; float precn2 = 0.f;
    // prime prefetch: chunk 0
    #pragma unroll
    for (int p = 0; p < 8; ++p) {
        int lin = p * 256 + tid, code = lin >> 5, seg = lin & 31;
        pre[p] = *(const uint4*)(cbw + (size_t)code * DIM + seg * 8);
    }
    if (tid < 64) precn2 = cn2w[tid];

    for (int pass = 0; pass < 2; ++pass) {
        for (int kc = 0; kc < NCHUNK; ++kc) {
            __syncthreads();           // cbuf free to overwrite
            #pragma unroll
            for (int p = 0; p < 8; ++p) {
                int lin = p * 256 + tid, code = lin >> 5, seg = lin & 31;
                *(uint4*)((char*)cbuf + swz(code, seg * 16)) = pre[p];
            }
            if (tid < 64) cn2buf[tid] = precn2;
            // prefetch next chunk (last chunk of pass 0 prefetches chunk 0 for pass 1)
            int nkc = (kc < NCHUNK - 1) ? kc + 1 : (pass == 0 ? 0 : -1);
            if (nkc >= 0) {
                int base = nkc * BKC;
                #pragma unroll
                for (int p = 0; p < 8; ++p) {
                    int lin = p * 256 + tid, code = lin >> 5, seg = lin & 31;
                    pre[p] = *(const uint4*)(cbw + (size_t)(base + code) * DIM + seg * 8);
                }
                if (tid < 64) precn2 = cn2w[base + tid];
            }
            __syncthreads();           // chunk staged

            #pragma unroll
            for (int nt = 0; nt < 4; ++nt) {
                f32x4 acc0 = {0.f, 0.f, 0.f, 0.f};
                f32x4 acc1 = {0.f, 0.f, 0.f, 0.f};
                int codeLocal = nt * 16 + li;
                #pragma unroll
                for (int kk = 0; kk < 8; ++kk) {
                    bf16x8 bfr = *(const bf16x8*)((const char*)cbuf +
                                   swz(codeLocal, kk * 64 + 16 * g));
                    acc0 = __builtin_amdgcn_mfma_f32_16x16x32_bf16(af[0][kk], bfr, acc0, 0, 0, 0);
                    acc1 = __builtin_amdgcn_mfma_f32_16x16x32_bf16(af[1][kk], bfr, acc1, 0, 0, 0);
                }
                int code = kc * BKC + codeLocal;
                float c2 = cn2buf[codeLocal];
                #pragma unroll
                for (int mi = 0; mi < 2; ++mi) {
                    f32x4 a = mi ? acc1 : acc0;
                    #pragma unroll
                    for (int rg = 0; rg < 4; ++rg) {
                        float s = c2 - 2.0f * a[rg];
                        if (pass == 0) {
                            minv[mi][rg] = fminf(minv[mi][rg], s);
                        } else if (s < rowm[mi][rg]) {
                            int rowloc = (2 * w + mi) * 16 + 4 * g + rg;
                            int slot = atomicAdd(&cnt[rowloc], 1);
                            if (slot < CAP) cand[rowloc * CAP + slot] = (unsigned short)code;
                        }
                    }
                }
            }
        }
        if (pass == 0) {
            // reduce per-row min across the 16 lanes sharing each row
            #pragma unroll
            for (int mi = 0; mi < 2; ++mi)
                #pragma unroll
                for (int rg = 0; rg < 4; ++rg) {
                    float v = minv[mi][rg];
                    v = fminf(v, __shfl_xor(v, 1));
                    v = fminf(v, __shfl_xor(v, 2));
                    v = fminf(v, __shfl_xor(v, 4));
                    v = fminf(v, __shfl_xor(v, 8));
                    if (li == 0) rowmin_s[(2 * w + mi) * 16 + 4 * g + rg] = v;
                }
            if (tid < BM) cnt[tid] = 0;
            __syncthreads();
            #pragma unroll
            for (int mi = 0; mi < 2; ++mi)
                #pragma unroll
                for (int rg = 0; rg < 4; ++rg)
                    rowm[mi][rg] = rowmin_s[(2 * w + mi) * 16 + 4 * g + rg] + MARGIN;
        }
    }
    __syncthreads();  // candidates complete

    // ---- refine: fp64 exact rescore, argmin with lowest-index tie-break ----
    for (int rr = 0; rr < 32; ++rr) {
        int rowloc = w * 32 + rr;
        int grow = rows0 + rowloc;
        int c = cnt[rowloc];
        bool fullscan = (c > CAP);
        int total = fullscan ? KCODES : c;
        const float* rrow = rsrc + (size_t)grow * DIM;
        double bestS = 1.0e300; int bestI = 0x7fffffff;
        for (int base = 0; base < total; base += 4) {
            int slot = base + g;
            bool valid = slot < total;
            int code = valid ? (fullscan ? slot : (int)cand[rowloc * CAP + slot]) : 0;
            const float* crow = cbf + (size_t)code * DIM;
            double dacc = 0.0, cacc = 0.0;
            #pragma unroll 4
            for (int ii = 0; ii < 16; ++ii) {
                int d = li + ii * 16;
                double cv = (double)crow[d];
                double rv = (double)rrow[d];
                dacc = fma(cv, rv, dacc);
                cacc = fma(cv, cv, cacc);
            }
            #pragma unroll
            for (int m = 1; m <= 8; m <<= 1) {
                dacc += __shfl_xor(dacc, m);
                cacc += __shfl_xor(cacc, m);
            }
            double s = valid ? (cacc - 2.0 * dacc) : 1.0e300;
            int ci = valid ? code : 0x7fffffff;
            #pragma unroll
            for (int m = 16; m <= 32; m <<= 1) {
                double so = __shfl_xor(s, m);
                int io = __shfl_xor(ci, m);
                if (so < s || (so == s && io < ci)) { s = so; ci = io; }
            }
            if (s < bestS || (s == bestS && ci < bestI)) { bestS = s; bestI = ci; }
        }
        if (l == 0) {
            winid[rowloc] = bestI;
            ids_out[(size_t)grow * LEVELS + level] = (float)bestI;
        }
    }
    __syncthreads();

    // ---- epilogue: gather q, zq[l] = zq[l-1] + (r + (q-r)), r' = r - q, loss ----
    float lacc = 0.f;
    for (int it = 0; it < 32; ++it) {
        int rowloc = it * 4 + (tid >> 6);
        int grow = rows0 + rowloc;
        int d0 = (tid & 63) * 4;
        int code = winid[rowloc];
        float4 q = *(const float4*)(cbf + (size_t)code * DIM + d0);
        float4 r = *(const float4*)(rsrc + (size_t)grow * DIM + d0);
        float4 zp = {0.f, 0.f, 0.f, 0.f};
        if (level > 0) zp = *(const float4*)(zqprev + (size_t)grow * DIM + d0);
        float dx = q.x - r.x, dy = q.y - r.y, dz = q.z - r.z, dw = q.w - r.w;
        float4 zo; // q_st = r + (q - r), matching the reference's fp32 ops
        zo.x = zp.x + (r.x + dx); zo.y = zp.y + (r.y + dy);
        zo.z = zp.z + (r.z + dz); zo.w = zp.w + (r.w + dw);
        *(float4*)(zqout + (size_t)grow * DIM + d0) = zo;
        if (rnext) {
            float4 rn; rn.x = -dx; rn.y = -dy; rn.z = -dz; rn.w = -dw;
            *(float4*)(rnext + (size_t)grow * DIM + d0) = rn;
        }
        lacc += dx * dx + dy * dy + dz * dz + dw * dw;
    }
    #pragma unroll
    for (int m = 32; m; m >>= 1) lacc += __shfl_xor(lacc, m);
    if (l == 0) wl[w] = lacc;
    __syncthreads();
    if (tid == 0)
        atomicAdd(loss_out, (wl[0] + wl[1] + wl[2] + wl[3]) * (1.25f / 16777216.f));
}

extern "C" void kernel_launch(void* const* d_in, const int* in_sizes, int n_in,
                              void* d_out, int out_size, void* d_ws, size_t ws_size,
                              hipStream_t stream) {
    const float* data = (const float*)d_in[0];
    const float* cb   = (const float*)d_in[1];
    float* out  = (float*)d_out;
    float* zq   = out;
    float* ids  = out + IDS_OFF;
    float* loss = out + LOSS_OFF;
    unsigned short* cbw = (unsigned short*)d_ws;                       // 2 MB bf16 codebook
    float* cn2w = (float*)((char*)d_ws + (size_t)LEVELS * KCODES * DIM * 2); // 16 KB
    float* rscr = zq + (size_t)3 * CH;  // zq_stack[3] slot doubles as residual scratch

    hipMemsetAsync(loss, 0, sizeof(float), stream);
    k_prep<<<LEVELS * KCODES, 64, 0, stream>>>(cb, cbw, cn2w);
    for (int lv = 0; lv < LEVELS; ++lv) {
        const float* rsrc   = (lv == 0) ? data : rscr;
        const float* zqprev = (lv == 0) ? nullptr : zq + (size_t)(lv - 1) * CH;
        float* zqout = zq + (size_t)lv * CH;
        float* rnext = (lv == 3) ? nullptr : rscr;
        k_score<<<NROWS / BM, 256, 0, stream>>>(
            rsrc, cb + (size_t)lv * KCODES * DIM, cbw + (size_t)lv * KCODES * DIM,
            cn2w + (size_t)lv * KCODES, zqprev, zqout, rnext, ids, loss, lv);
    }
}

// Round 2
// 1154.673 us; speedup vs baseline: 12.1242x; 12.1242x over previous
//
#include <hip/hip_runtime.h>
#include <hip/hip_bf16.h>

// RQ-VAE residual quantization, MI355X gfx950.
// data [65536][256] f32, codebooks [4][1024][256] f32.
// out = [zq_stack 4*65536*256][semantic_ids 65536*4 (as float)][loss 1], all f32.
//
// Per level: bf16-MFMA approximate scores (pass 0: row-min, pass 1: collect
// candidates within MARGIN) + lane-parallel fp64 exact rescore (atomicMin on
// packed score|code key) + fused gather/update epilogue. The bf16 codebook is
// pre-tiled in MFMA fragment order so staging (global_load_lds) and ds_read
// are both perfectly linear (zero bank conflicts). Residual r lives in the
// zq_stack[3] slot of d_out (read-before-write per thread at level 3).

#define NROWS   65536
#define DIM     256
#define KCODES  1024
#define LEVELS  4
#define CH      (NROWS * DIM)
#define IDS_OFF (LEVELS * CH)
#define LOSS_OFF (IDS_OFF + NROWS * LEVELS)

#define BM      128
#define NCHUNK  16
#define CAP     32
#define MARGIN  8.0f
#define CHUNK_USH 16384          // 64 codes * 256 bf16
#define LVL_USH   262144         // 1024 * 256

typedef __attribute__((ext_vector_type(8))) short bf16x8;
typedef __attribute__((ext_vector_type(4))) float f32x4;
typedef const __attribute__((address_space(1))) void* gp_t;
typedef __attribute__((address_space(3))) void* lp_t;

__device__ __forceinline__ unsigned short f2bf(float x) {
    __hip_bfloat16 h = __float2bfloat16(x);
    unsigned short r; __builtin_memcpy(&r, &h, 2); return r;
}
__device__ __forceinline__ float bf2f(unsigned short u) {
    __hip_bfloat16 h; __builtin_memcpy(&h, &u, 2); return __bfloat162float(h);
}

// ---- k_prep: bf16 codebook in fragment-tiled layout + sum(c_bf16^2) ----
// Layout (ushort idx): ((((L*16+chunk)*4+nt)*8+kk)*64 + (g*16+li))*8 + h
//   code c: chunk=c>>6, nt=(c>>4)&3, li=c&15;  byte b: kk=b>>6, g=(b>>4)&3.
__global__ __launch_bounds__(64) void k_prep(const float* __restrict__ cb,
                                             unsigned short* __restrict__ cbw,
                                             float* __restrict__ cn2w) {
    int cr = blockIdx.x;                 // level*1024 + code
    int L = cr >> 10, c = cr & 1023;
    int l = threadIdx.x;                 // handles floats l*4..l*4+3
    float4 v = *(const float4*)(cb + (size_t)cr * DIM + l * 4);
    ushort4 st;
    st.x = f2bf(v.x); st.y = f2bf(v.y); st.z = f2bf(v.z); st.w = f2bf(v.w);
    int b = l * 8;                       // byte position in the 512B bf16 row
    int kk = b >> 6, g = (b >> 4) & 3, h = (b & 15) >> 1;
    int idx = ((((L * 16 + (c >> 6)) * 4 + ((c >> 4) & 3)) * 8 + kk) * 64
               + (g * 16 + (c & 15))) * 8 + h;
    *(ushort4*)(cbw + idx) = st;
    float f0 = bf2f(st.x), f1 = bf2f(st.y), f2 = bf2f(st.z), f3 = bf2f(st.w);
    float sq = f0 * f0 + f1 * f1 + f2 * f2 + f3 * f3;
    #pragma unroll
    for (int m = 32; m; m >>= 1) sq += __shfl_xor(sq, m);
    if (l == 0) cn2w[cr] = sq;
}

// ---- k_score: per-level approx scores + exact refine + update ----
__global__ __launch_bounds__(256) void k_score(
    const float* rsrc,                        // residual (or data) [N][256]
    const float* __restrict__ cbf,            // f32 codebook, this level
    const unsigned short* __restrict__ cbwL,  // frag-tiled bf16 codebook, this level
    const float* __restrict__ cn2L,           // [1024] sum of bf16-c^2
    const float* zqprev, float* zqout, float* rnext,
    float* __restrict__ ids_out,
    double* __restrict__ blockpart,
    int level)
{
    __shared__ unsigned short cbuf[2 * CHUNK_USH];   // 64 KB double buffer
    __shared__ float rowmin_s[BM];
    __shared__ unsigned short cand[BM * CAP];        // 8 KB
    __shared__ int cnt[BM];
    __shared__ unsigned long long winkey[BM];
    __shared__ int winid[BM];
    __shared__ float wl[4];

    const int tid = threadIdx.x;
    const int w = tid >> 6, l = tid & 63;
    const int g = l >> 4, li = l & 15;
    const int rows0 = blockIdx.x * BM;

    // stage chunk T into buffer T&1 (linear DMA: 8 x 1KB per wave)
    #define STAGE(T) do {                                                      \
        int _kc = (T) & 15, _bs = (T) & 1;                                     \
        const unsigned short* _g = cbwL + _kc * CHUNK_USH + (w * 8) * 512;     \
        unsigned short* _d = &cbuf[_bs * CHUNK_USH + (w * 8) * 512];           \
        _Pragma("unroll")                                                      \
        for (int _r = 0; _r < 8; ++_r)                                         \
            __builtin_amdgcn_global_load_lds((gp_t)(_g + _r * 512 + l * 8),    \
                                             (lp_t)(_d + _r * 512), 16, 0, 0); \
    } while (0)

    STAGE(0);

    // A-fragments (r rows in bf16, registers, reused both passes)
    bf16x8 af[2][8];
    #pragma unroll
    for (int mi = 0; mi < 2; ++mi) {
        int row = rows0 + (2 * w + mi) * 16 + li;
        const float* rp = rsrc + (size_t)row * DIM;
        #pragma unroll
        for (int kk = 0; kk < 8; ++kk) {
            int d0 = kk * 32 + 8 * g;
            float4 v0 = *(const float4*)(rp + d0);
            float4 v1 = *(const float4*)(rp + d0 + 4);
            bf16x8 t;
            t[0] = (short)f2bf(v0.x); t[1] = (short)f2bf(v0.y);
            t[2] = (short)f2bf(v0.z); t[3] = (short)f2bf(v0.w);
            t[4] = (short)f2bf(v1.x); t[5] = (short)f2bf(v1.y);
            t[6] = (short)f2bf(v1.z); t[7] = (short)f2bf(v1.w);
            af[mi][kk] = t;
        }
    }

    float minv[2][4], rowm[2][4];
    #pragma unroll
    for (int mi = 0; mi < 2; ++mi)
        #pragma unroll
        for (int rg = 0; rg < 4; ++rg) { minv[mi][rg] = 3.0e38f; rowm[mi][rg] = 0.f; }

    __syncthreads();   // chunk 0 staged (syncthreads drains vmcnt)

    for (int pass = 0; pass < 2; ++pass) {
        for (int kc = 0; kc < NCHUNK; ++kc) {
            int t = pass * 16 + kc;
            if (t < 31) STAGE(t + 1);          // load next chunk under compute
            const unsigned short* fb = &cbuf[(t & 1) * CHUNK_USH];
            #pragma unroll
            for (int nt = 0; nt < 4; ++nt) {
                f32x4 acc0 = {0.f, 0.f, 0.f, 0.f};
                f32x4 acc1 = {0.f, 0.f, 0.f, 0.f};
                const unsigned short* fp8 = fb + (nt * 8) * 512 + l * 8;
                #pragma unroll
                for (int kk = 0; kk < 8; ++kk) {
                    bf16x8 bfr = *(const bf16x8*)(fp8 + kk * 512);
                    acc0 = __builtin_amdgcn_mfma_f32_16x16x32_bf16(af[0][kk], bfr, acc0, 0, 0, 0);
                    acc1 = __builtin_amdgcn_mfma_f32_16x16x32_bf16(af[1][kk], bfr, acc1, 0, 0, 0);
                }
                float c2 = cn2L[kc * 64 + nt * 16 + li];
                #pragma unroll
                for (int mi = 0; mi < 2; ++mi) {
                    f32x4 a = mi ? acc1 : acc0;
                    #pragma unroll
                    for (int rg = 0; rg < 4; ++rg) {
                        float s = __builtin_fmaf(-2.f, a[rg], c2);
                        if (pass == 0) {
                            minv[mi][rg] = fminf(minv[mi][rg], s);
                        } else if (s < rowm[mi][rg]) {
                            int rowloc = (2 * w + mi) * 16 + 4 * g + rg;
                            int slot = atomicAdd(&cnt[rowloc], 1);
                            if (slot < CAP)
                                cand[rowloc * CAP + slot] = (unsigned short)(kc * 64 + nt * 16 + li);
                        }
                    }
                }
            }
            __syncthreads();   // chunk t reads done + chunk t+1 staged
        }
        if (pass == 0) {
            #pragma unroll
            for (int mi = 0; mi < 2; ++mi)
                #pragma unroll
                for (int rg = 0; rg < 4; ++rg) {
                    float v = minv[mi][rg];
                    v = fminf(v, __shfl_xor(v, 1));
                    v = fminf(v, __shfl_xor(v, 2));
                    v = fminf(v, __shfl_xor(v, 4));
                    v = fminf(v, __shfl_xor(v, 8));
                    if (li == 0) rowmin_s[(2 * w + mi) * 16 + 4 * g + rg] = v;
                }
            if (tid < BM) { cnt[tid] = 0; winkey[tid] = ~0ULL; }
            __syncthreads();
            #pragma unroll
            for (int mi = 0; mi < 2; ++mi)
                #pragma unroll
                for (int rg = 0; rg < 4; ++rg)
                    rowm[mi][rg] = rowmin_s[(2 * w + mi) * 16 + 4 * g + rg] + MARGIN;
        }
    }

    // ---- refine: lane-parallel fp64 exact rescore, atomicMin packed key ----
    auto refine_pair = [&](int row, int code) {
        const float* rrow = rsrc + (size_t)(rows0 + row) * DIM;
        const float* crow = cbf + (size_t)code * DIM;
        double dd0 = 0.0, dd1 = 0.0, cc0 = 0.0, cc1 = 0.0;
        #pragma unroll 4
        for (int d = 0; d < DIM; d += 8) {
            float4 c0 = *(const float4*)(crow + d);
            float4 c1 = *(const float4*)(crow + d + 4);
            float4 r0 = *(const float4*)(rrow + d);
            float4 r1 = *(const float4*)(rrow + d + 4);
            dd0 = fma((double)c0.x, (double)r0.x, dd0);
            dd0 = fma((double)c0.y, (double)r0.y, dd0);
            dd0 = fma((double)c0.z, (double)r0.z, dd0);
            dd0 = fma((double)c0.w, (double)r0.w, dd0);
            dd1 = fma((double)c1.x, (double)r1.x, dd1);
            dd1 = fma((double)c1.y, (double)r1.y, dd1);
            dd1 = fma((double)c1.z, (double)r1.z, dd1);
            dd1 = fma((double)c1.w, (double)r1.w, dd1);
            cc0 = fma((double)c0.x, (double)c0.x, cc0);
            cc0 = fma((double)c0.y, (double)c0.y, cc0);
            cc0 = fma((double)c0.z, (double)c0.z, cc0);
            cc0 = fma((double)c0.w, (double)c0.w, cc0);
            cc1 = fma((double)c1.x, (double)c1.x, cc1);
            cc1 = fma((double)c1.y, (double)c1.y, cc1);
            cc1 = fma((double)c1.z, (double)c1.z, cc1);
            cc1 = fma((double)c1.w, (double)c1.w, cc1);
        }
        double s = (cc0 + cc1) - 2.0 * (dd0 + dd1);
        long long xb = __double_as_longlong(s);
        unsigned long long o = (xb < 0) ? (unsigned long long)(~xb)
                                        : ((unsigned long long)xb | 0x8000000000000000ULL);
        atomicMin(&winkey[row], (o & ~1023ULL) | (unsigned long long)code);
    };

    for (int p = tid; p < BM * CAP; p += 256) {
        int row = p >> 5, slot = p & (CAP - 1);
        int c = cnt[row];
        if (c <= CAP && slot < c) refine_pair(row, (int)cand[row * CAP + slot]);
    }
    for (int row = 0; row < BM; ++row) {        // sound fallback, ~never taken
        if (cnt[row] > CAP)
            for (int code = tid; code < KCODES; code += 256) refine_pair(row, code);
    }
    __syncthreads();
    if (tid < BM) {
        int best = (int)(winkey[tid] & 1023ULL);
        winid[tid] = best;
        ids_out[(size_t)(rows0 + tid) * LEVELS + level] = (float)best;
    }
    __syncthreads();

    // ---- epilogue: gather q, zq[l] = zq[l-1] + (r + (q-r)), r' = r - q, loss ----
    float lacc = 0.f;
    for (int it = 0; it < 32; ++it) {
        int rowloc = it * 4 + w;
        int grow = rows0 + rowloc;
        int d0 = l * 4;
        int code = winid[rowloc];
        float4 q = *(const float4*)(cbf + (size_t)code * DIM + d0);
        float4 r = *(const float4*)(rsrc + (size_t)grow * DIM + d0);
        float4 zp = {0.f, 0.f, 0.f, 0.f};
        if (zqprev) zp = *(const float4*)(zqprev + (size_t)grow * DIM + d0);
        float dx = q.x - r.x, dy = q.y - r.y, dz = q.z - r.z, dw = q.w - r.w;
        float4 zo;
        zo.x = zp.x + (r.x + dx); zo.y = zp.y + (r.y + dy);
        zo.z = zp.z + (r.z + dz); zo.w = zp.w + (r.w + dw);
        *(float4*)(zqout + (size_t)grow * DIM + d0) = zo;
        if (rnext) {
            float4 rn; rn.x = -dx; rn.y = -dy; rn.z = -dz; rn.w = -dw;
            *(float4*)(rnext + (size_t)grow * DIM + d0) = rn;
        }
        lacc += dx * dx + dy * dy + dz * dz + dw * dw;
    }
    #pragma unroll
    for (int m = 32; m; m >>= 1) lacc += __shfl_xor(lacc, m);
    if (l == 0) wl[w] = lacc;
    __syncthreads();
    if (tid == 0)
        blockpart[level * (NROWS / BM) + blockIdx.x] =
            (double)wl[0] + (double)wl[1] + (double)wl[2] + (double)wl[3];
}

// ---- k_loss: deterministic fixed-order reduction of block partials ----
__global__ __launch_bounds__(256) void k_loss(const double* __restrict__ part,
                                              float* __restrict__ loss) {
    __shared__ double sd[256];
    int tid = threadIdx.x;
    double a = 0.0;
    #pragma unroll
    for (int i = 0; i < 8; ++i) a += part[i * 256 + tid];   // 2048 entries
    sd[tid] = a; __syncthreads();
    for (int s = 128; s > 0; s >>= 1) {
        if (tid < s) sd[tid] += sd[tid + s];
        __syncthreads();
    }
    if (tid == 0) *loss = (float)(sd[0] * (1.25 / 16777216.0));
}

extern "C" void kernel_launch(void* const* d_in, const int* in_sizes, int n_in,
                              void* d_out, int out_size, void* d_ws, size_t ws_size,
                              hipStream_t stream) {
    const float* data = (const float*)d_in[0];
    const float* cb   = (const float*)d_in[1];
    float* out  = (float*)d_out;
    float* zq   = out;
    float* ids  = out + IDS_OFF;
    float* loss = out + LOSS_OFF;
    unsigned short* cbw = (unsigned short*)d_ws;                        // 2 MB frag-tiled bf16
    float*  cn2w  = (float*)((char*)d_ws + (size_t)LEVELS * LVL_USH * 2);          // +2MB, 16KB
    double* bpart = (double*)((char*)d_ws + (size_t)LEVELS * LVL_USH * 2 + 16384); // 16KB
    float* rscr = zq + (size_t)3 * CH;   // zq_stack[3] slot doubles as residual scratch

    k_prep<<<LEVELS * KCODES, 64, 0, stream>>>(cb, cbw, cn2w);
    for (int lv = 0; lv < LEVELS; ++lv) {
        const float* rsrc   = (lv == 0) ? data : rscr;
        const float* zqprev = (lv == 0) ? nullptr : zq + (size_t)(lv - 1) * CH;
        float* zqout = zq + (size_t)lv * CH;
        float* rnext = (lv == 3) ? nullptr : rscr;
        k_score<<<NROWS / BM, 256, 0, stream>>>(
            rsrc, cb + (size_t)lv * KCODES * DIM, cbw + (size_t)lv * LVL_USH,
            cn2w + (size_t)lv * KCODES, zqprev, zqout, rnext, ids, bpart, lv);
    }
    k_loss<<<1, 256, 0, stream>>>(bpart, loss);
}